// Round 1
// 930.772 us; speedup vs baseline: 1.0108x; 1.0108x over previous
//
#include <hip/hip_runtime.h>
#include <stdint.h>

typedef unsigned short u16;
typedef unsigned int   u32;

constexpr int SS = 2048, EE = 1024, HH = 16, DD = 64, LL = 6, FF = 4096;

typedef __bf16 bf16x8 __attribute__((ext_vector_type(8)));
typedef float  f32x4  __attribute__((ext_vector_type(4)));

#define DEV __device__ __forceinline__
#define AS1 __attribute__((address_space(1)))
#define AS3 __attribute__((address_space(3)))

DEV u16 f2bf(float f) {
    u32 u = __builtin_bit_cast(u32, f);
    u += 0x7FFFu + ((u >> 16) & 1u);
    return (u16)(u >> 16);
}

DEV float bf2f(u16 v) { return __builtin_bit_cast(float, (u32)v << 16); }

DEV void store_bf4(u16* p, float a, float b, float c, float d) {
    u32 lo = (u32)f2bf(a) | ((u32)f2bf(b) << 16);
    u32 hi = (u32)f2bf(c) | ((u32)f2bf(d) << 16);
    *(uint2*)p = make_uint2(lo, hi);
}

DEV void gload16(const void* g, void* l) {
    __builtin_amdgcn_global_load_lds((const AS1 void*)g, (AS3 void*)l, 16, 0, 0);
}

DEV f32x4 mfma16(bf16x8 a, bf16x8 b, f32x4 c) {
    return __builtin_amdgcn_mfma_f32_16x16x32_bf16(a, b, c, 0, 0, 0);
}

// single-instruction 2^x (VOP1 v_exp_f32)
DEV float exp2_fast(float x) {
    float r;
    asm("v_exp_f32 %0, %1" : "=v"(r) : "v"(x));
    return r;
}

// kv-permutation: actual kv -> PV-consumption slot (bit-6 transparent)
DEV int kvperm(int c) {
    return (c & 32) | ((c & 12) << 1) | ((c & 16) >> 2) | (c & 3);
}

// XCD-chunked bijective swizzle over nwg blocks (nwg % 8 == 0)
DEV int xcd_swz(int flat, int nwg) {
    int chunk = nwg >> 3;
    return (flat & 7) * chunk + (flat >> 3);
}

// ---------------- workspace layout (bytes) ----------------
constexpr size_t ALGN(size_t x) { return (x + 255) & ~(size_t)255; }
constexpr size_t OFF_WF   = 0;                                            // [3][L][1024][1024] bf16
constexpr size_t OFF_HWT  = ALGN(OFF_WF   + (size_t)3*LL*1024*1024*2);    // [3][96][64][64] bf16
constexpr size_t OFF_WSHT = ALGN(OFF_HWT  + (size_t)3*96*4096*2);         // [3][1024][64] bf16
constexpr size_t OFF_HB   = ALGN(OFF_WSHT + (size_t)3*1024*64*2);         // [L][3][H][64] f32
constexpr size_t OFF_WOT  = ALGN(OFF_HB   + (size_t)LL*3*HH*64*4);        // [L][E][E] bf16
constexpr size_t OFF_W1T  = ALGN(OFF_WOT  + (size_t)LL*EE*EE*2);          // [L][FF][E] bf16
constexpr size_t OFF_W2T  = ALGN(OFF_W1T  + (size_t)LL*FF*EE*2);          // [L][E][FF] bf16
constexpr size_t OFF_HBF  = ALGN(OFF_W2T  + (size_t)LL*EE*FF*2);          // h bf16 [S][E] (residual chain)
// transient union: [QKVH 2*16*S*64 | VT 1024*S | CAT S*E] bf16 == F1 [S][FF] bf16
constexpr size_t OFF_QKVH = ALGN(OFF_HBF  + (size_t)SS*EE*2);
constexpr size_t OFF_VT   = OFF_QKVH + (size_t)2*HH*SS*64*2;
constexpr size_t OFF_CAT  = OFF_VT   + (size_t)1024*SS*2;
constexpr size_t OFF_F1   = OFF_QKVH;                                     // alias
constexpr size_t OFF_OF   = ALGN(OFF_CAT + (size_t)SS*EE*2);              // [4][S][E] bf16 partials

// ---------------- prep kernels ----------------
__global__ void pos_add(const float* __restrict__ x, u16* __restrict__ hb) {
    const int row = blockIdx.x, tid = threadIdx.x;
    float4 x4 = ((const float4*)(x + (size_t)row * EE))[tid];
    float v[4] = {x4.x, x4.y, x4.z, x4.w};
    float y[4];
#pragma unroll
    for (int j = 0; j < 4; ++j) {
        int e = tid * 4 + j;
        float ang = (float)row * expf((float)e * (-9.210340371976184f / 1024.f));
        float pe = ((row & 1) == 0) ? sinf(ang) : cosf(ang);
        y[j] = v[j] + pe;
    }
    store_bf4(hb + (size_t)row * EE + tid * 4, y[0], y[1], y[2], y[3]);
}

__global__ void pack_bias(const float* __restrict__ bk, const float* __restrict__ bq,
                          const float* __restrict__ bv, float* __restrict__ dst) {
    int i = blockIdx.x * 256 + threadIdx.x;      // [l][t][h][64]
    if (i >= LL * 3 * HH * 64) return;
    int d = i & 63;
    int hh = (i >> 6) & 15;
    int lt = i >> 10;
    int t = lt % 3, l = lt / 3;
    const float* s = (t == 0) ? bk : (t == 1) ? bq : bv;
    dst[i] = s[((size_t)l * HH + hh) * 64 + d];
}

// 64x64 tile transpose-cast body (src f32 [R][C] -> dst bf16 [C][R])
DEV void tile_t64(const float* src, u16* dst, int R, int C, int c0, int r0,
                  float (*t)[65], int tid) {
    const int lr = tid >> 4, lc4 = (tid & 15) * 4;
#pragma unroll
    for (int i = 0; i < 4; ++i) {
        int r = i * 16 + lr;
        float4 v = *(const float4*)(src + (size_t)(r0 + r) * C + c0 + lc4);
        t[r][lc4] = v.x; t[r][lc4 + 1] = v.y; t[r][lc4 + 2] = v.z; t[r][lc4 + 3] = v.w;
    }
    __syncthreads();
    const int cr = tid >> 3, rr8 = (tid & 7) * 8;
#pragma unroll
    for (int i = 0; i < 2; ++i) {
        int cc = i * 32 + cr;
        u16 tmp[8];
#pragma unroll
        for (int j = 0; j < 8; ++j) tmp[j] = f2bf(t[rr8 + j][cc]);
        *(uint4*)(dst + (size_t)(c0 + cc) * R + r0 + rr8) = *(uint4*)tmp;
    }
}

// f32 [b][R][C] -> bf16 [b][C][R], 64x64 tiles
__global__ void transpose_cast64(const float* __restrict__ src, u16* __restrict__ dst,
                                 int R, int C, long sSrc, long sDst) {
    __shared__ float t[64][65];
    const int b = blockIdx.z;
    tile_t64(src + (size_t)b * sSrc, dst + (size_t)b * sDst, R, C,
             blockIdx.x * 64, blockIdx.y * 64, t, threadIdx.x);
}

// merged per-head weight transpose: z in [0,288), t=z/96, head-idx=z%96
__global__ void hw_t3(const float* __restrict__ s0, const float* __restrict__ s1,
                      const float* __restrict__ s2, u16* __restrict__ dst) {
    __shared__ float t[64][65];
    const int z = blockIdx.z;
    const float* src = (z < 96 ? s0 : z < 192 ? s1 : s2) + (size_t)(z % 96) * 4096;
    tile_t64(src, dst + (size_t)z * 4096, 64, 64, 0, 0, t, threadIdx.x);
}

// merged shared-weight transpose: z in [0,3)
__global__ void wsh_t3(const float* __restrict__ s0, const float* __restrict__ s1,
                       const float* __restrict__ s2, u16* __restrict__ dst) {
    __shared__ float t[64][65];
    const int z = blockIdx.z;
    const float* src = (z == 0) ? s0 : (z == 1) ? s1 : s2;
    tile_t64(src, dst + (size_t)z * 65536, 64, 1024, blockIdx.x * 64, 0, t, threadIdx.x);
}

// ---------------- TN GEMM, double-buffered, XCD-swizzled ----------------
// out is always bf16. SPLITK: out offset z*M*N (K split by grid.z).
// BATCH: z indexes independent problems with strides zsA/zsB/zsC.
// BIASMODE: 0 none, 1 per-col
template<int BIASMODE, bool RELU, bool SPLITK, bool BATCH>
__launch_bounds__(256)
__global__ void gemm_std(const u16* __restrict__ A, const u16* __restrict__ B,
                         const float* __restrict__ bias, u16* __restrict__ Cb,
                         int M, int N, int K, int lda, int ldb,
                         long zsA, long zsB, long zsC) {
    __shared__ u16 As[2][128 * 64];
    __shared__ u16 Bs[2][128 * 64];
    const int gx = gridDim.x;
    const int swz = xcd_swz(blockIdx.y * gx + blockIdx.x, gx * gridDim.y);
    const int bn = swz % gx, bm = swz / gx, z = blockIdx.z;
    const int tid = threadIdx.x, w = tid >> 6;
    const int lane = tid & 63, l15 = lane & 15, hi = lane >> 4;
    const int wm = w >> 1, wn = w & 1;
    const u16* Ab = A + (size_t)bm * 128 * lda + (SPLITK ? (size_t)z * K : 0) + (BATCH ? (size_t)z * zsA : 0);
    const u16* Bb = B + (size_t)bn * 128 * ldb + (SPLITK ? (size_t)z * K : 0) + (BATCH ? (size_t)z * zsB : 0);
    const size_t coff = SPLITK ? (size_t)z * M * N : (BATCH ? (size_t)z * zsC : 0);
    const int tr = tid >> 3, tp = tid & 7;

    f32x4 acc[4][4];
#pragma unroll
    for (int i = 0; i < 4; ++i)
#pragma unroll
        for (int j = 0; j < 4; ++j) acc[i][j] = f32x4{0.f, 0.f, 0.f, 0.f};

    auto STAGE = [&](int b, int kt) {
        const u16* Abk = Ab + kt + (size_t)tr * lda + tp * 8;
        const u16* Bbk = Bb + kt + (size_t)tr * ldb + tp * 8;
#pragma unroll
        for (int i = 0; i < 4; ++i) {
            gload16(Abk + (size_t)i * 32 * lda, &As[b][(i * 256 + w * 64) * 8]);
            gload16(Bbk + (size_t)i * 32 * ldb, &Bs[b][(i * 256 + w * 64) * 8]);
        }
    };

    STAGE(0, 0);
    __syncthreads();
    int buf = 0;

    for (int kt = 0; kt < K; kt += 64) {
        if (kt + 64 < K) STAGE(buf ^ 1, kt + 64);
#pragma unroll
        for (int kk = 0; kk < 2; ++kk) {
            bf16x8 af[4], bf[4];
#pragma unroll
            for (int mi = 0; mi < 4; ++mi)
                af[mi] = *(const bf16x8*)&As[buf][(wm * 64 + mi * 16 + l15) * 64 + kk * 32 + hi * 8];
#pragma unroll
            for (int ni = 0; ni < 4; ++ni)
                bf[ni] = *(const bf16x8*)&Bs[buf][(wn * 64 + ni * 16 + l15) * 64 + kk * 32 + hi * 8];
#pragma unroll
            for (int mi = 0; mi < 4; ++mi)
#pragma unroll
                for (int ni = 0; ni < 4; ++ni)
                    acc[mi][ni] = mfma16(af[mi], bf[ni], acc[mi][ni]);
        }
        __syncthreads();
        buf ^= 1;
    }

#pragma unroll
    for (int mi = 0; mi < 4; ++mi) {
        int rg = bm * 128 + wm * 64 + mi * 16 + hi * 4;
#pragma unroll
        for (int ni = 0; ni < 4; ++ni) {
            int cg = bn * 128 + wn * 64 + ni * 16 + l15;
            float bc = (BIASMODE == 1) ? bias[cg] : 0.f;
#pragma unroll
            for (int r = 0; r < 4; ++r) {
                float v = acc[mi][ni][r] + bc;
                if (RELU) v = fmaxf(v, 0.f);
                Cb[coff + (size_t)(rg + r) * N + cg] = f2bf(v);
            }
        }
    }
}

// QKV GEMM (dbuf, swizzled): A = h bf16 [S][E]; B = WF sections (t = bn>>3); N=3072
// t<2 -> QKVH[t][h][s][d] (Q pre-scaled by 0.125*log2e); t==2 -> VT[hd][psi(s)]
__launch_bounds__(256)
__global__ void gemm_qkv(const u16* __restrict__ A, const u16* __restrict__ WF, int l,
                         const float* __restrict__ bias, u16* __restrict__ QKVH,
                         u16* __restrict__ VT) {
    __shared__ u16 As[2][128 * 64];
    __shared__ u16 Bs[2][128 * 64];
    const int gx = gridDim.x;
    const int swz = xcd_swz(blockIdx.y * gx + blockIdx.x, gx * gridDim.y);
    const int bn = swz % gx, bm = swz / gx;
    const int tid = threadIdx.x, w = tid >> 6;
    const int lane = tid & 63, l15 = lane & 15, hi = lane >> 4;
    const int wm = w >> 1, wn = w & 1;
    const int t = bn >> 3;
    const u16* Ab = A + (size_t)bm * 128 * 1024;
    const u16* Bb = WF + (((size_t)(t * 6 + l)) << 20) + (size_t)(bn & 7) * 128 * 1024;
    const int tr = tid >> 3, tp = tid & 7;

    f32x4 acc[4][4];
#pragma unroll
    for (int i = 0; i < 4; ++i)
#pragma unroll
        for (int j = 0; j < 4; ++j) acc[i][j] = f32x4{0.f, 0.f, 0.f, 0.f};

    auto STAGE = [&](int b, int kt) {
        const u16* Abk = Ab + kt + (size_t)tr * 1024 + tp * 8;
        const u16* Bbk = Bb + kt + (size_t)tr * 1024 + tp * 8;
#pragma unroll
        for (int i = 0; i < 4; ++i) {
            gload16(Abk + (size_t)i * 32 * 1024, &As[b][(i * 256 + w * 64) * 8]);
            gload16(Bbk + (size_t)i * 32 * 1024, &Bs[b][(i * 256 + w * 64) * 8]);
        }
    };

    STAGE(0, 0);
    __syncthreads();
    int buf = 0;

    for (int kt = 0; kt < 1024; kt += 64) {
        if (kt + 64 < 1024) STAGE(buf ^ 1, kt + 64);
#pragma unroll
        for (int kk = 0; kk < 2; ++kk) {
            bf16x8 af[4], bf[4];
#pragma unroll
            for (int mi = 0; mi < 4; ++mi)
                af[mi] = *(const bf16x8*)&As[buf][(wm * 64 + mi * 16 + l15) * 64 + kk * 32 + hi * 8];
#pragma unroll
            for (int ni = 0; ni < 4; ++ni)
                bf[ni] = *(const bf16x8*)&Bs[buf][(wn * 64 + ni * 16 + l15) * 64 + kk * 32 + hi * 8];
#pragma unroll
            for (int mi = 0; mi < 4; ++mi)
#pragma unroll
                for (int ni = 0; ni < 4; ++ni)
                    acc[mi][ni] = mfma16(af[mi], bf[ni], acc[mi][ni]);
        }
        __syncthreads();
        buf ^= 1;
    }

    if (t < 2) {
        const float sc = (t == 1) ? 0.18033688011112042f : 1.f;  // Q: 0.125 * log2(e)
#pragma unroll
        for (int mi = 0; mi < 4; ++mi) {
            int rg = bm * 128 + wm * 64 + mi * 16 + hi * 4;
#pragma unroll
            for (int ni = 0; ni < 4; ++ni) {
                int cg = bn * 128 + wn * 64 + ni * 16 + l15;
                int hd = cg & 1023, hh = hd >> 6, d = hd & 63;
                float bv = bias[cg];
                u16* dst = QKVH + (((size_t)(t * 16 + hh) * SS) + rg) * 64 + d;
#pragma unroll
                for (int r = 0; r < 4; ++r)
                    dst[(size_t)r * 64] = f2bf((acc[mi][ni][r] + bv) * sc);
            }
        }
    } else {
#pragma unroll
        for (int mi = 0; mi < 4; ++mi) {
            int s0 = bm * 128 + wm * 64 + mi * 16 + hi * 4;
            int ps = (s0 & ~63) | kvperm(s0 & 63);   // r in 0..3 stays contiguous
#pragma unroll
            for (int ni = 0; ni < 4; ++ni) {
                int cg = bn * 128 + wn * 64 + ni * 16 + l15;
                int hd = cg & 1023;
                float bv = bias[cg];
                u16 tmp[4];
#pragma unroll
                for (int r = 0; r < 4; ++r) tmp[r] = f2bf(acc[mi][ni][r] + bv);
                *(uint2*)(VT + (size_t)hd * SS + ps) = *(uint2*)tmp;
            }
        }
    }
}

// ---------------- flash attention (swapped QK^T, exp2 softmax, KVBLK=128) ----------------
// kv-slice-per-wave: each of the 4 waves owns a 32-kv slice of the 128-kv tile for ALL 64
// q-rows of the block (Q register-resident: 8 frags). K/V fragments are read from LDS once
// and reused across the 4 q-groups -> 8 ds_read_b128 per wave per tile (was 32): the LDS
// pipe (CU-shared, 12cyc/b128) drops below the MFMA pipe (36 mfma ~ 175cyc) -> MFMA-bound.
// Per-wave partial O/l (over its kv quarter) is legal because softmax is max-free
// (log2-domain, deferred guard); one cross-wave LDS reduction per block at the end, with
// per-wave mrun reconciled via 2^(mrun_w - max).
__launch_bounds__(256)
__global__ void attn_fwd(const u16* __restrict__ QKVH, const u16* __restrict__ VT,
                         u16* __restrict__ cat) {
    const int logical = (blockIdx.x & 7) * 64 + (blockIdx.x >> 3);  // bijective: 512 = 8 x 64
    const int h = logical >> 5, qt = logical & 31;
    const int tid = threadIdx.x, w = tid >> 6, lane = tid & 63;
    const int l15 = lane & 15, hi = lane >> 4;
    // main loop: [0,8192) Ks buf0 | [8192,16384) Ks buf1 | [16384,24576) Vs buf0 | ... (u16)
    // epilogue reuse: P4 f32[4][64][65] | sred f32[4][64] | smr f32[4]
    __shared__ __align__(16) u16 smem[33824];

    const u16* qb = QKVH + (((size_t)(16 + h) * SS) + qt * 64) * 64;
    const u16* kb = QKVH + ((size_t)h * SS) * 64;
    const u16* vb = VT + (size_t)h * 64 * SS;

    // all 64 q-rows of the block, register-resident per wave
    bf16x8 bq[4][2];
#pragma unroll
    for (int qg = 0; qg < 4; ++qg) {
        bq[qg][0] = *(const bf16x8*)(qb + (qg * 16 + l15) * 64 + hi * 8);
        bq[qg][1] = *(const bf16x8*)(qb + (qg * 16 + l15) * 64 + 32 + hi * 8);
    }
    bf16x8 ONES;
#pragma unroll
    for (int i = 0; i < 8; ++i) ONES[i] = (__bf16)1.0f;

    f32x4 oacc[4][4];   // [qg][di], q = qg*16 + hi*4 + r, d = di*16 + l15
#pragma unroll
    for (int i = 0; i < 4; ++i)
#pragma unroll
        for (int j = 0; j < 4; ++j) oacc[i][j] = f32x4{0.f, 0.f, 0.f, 0.f};
    f32x4 sacc[4];      // [qg] row sums, q = qg*16 + hi*4 + r
#pragma unroll
    for (int i = 0; i < 4; ++i) sacc[i] = f32x4{0.f, 0.f, 0.f, 0.f};
    float mrun = 0.f;

    auto STAGE = [&](int buf, int t) {
#pragma unroll
        for (int j = 0; j < 4; ++j) {
            int fl = j * 256 + tid;                     // 0..1023 chunk id
            int kr = fl >> 3, kc = (fl & 7) ^ (kr & 7); // K: 128 rows x 8 chunks
            gload16(kb + ((size_t)(t * 128 + kr)) * 64 + kc * 8, smem + buf * 8192 + fl * 8);
            int vr = fl >> 4, vc = (fl & 15) ^ (vr & 7); // V: 64 d-rows x 16 chunks
            gload16(vb + (size_t)vr * SS + t * 128 + vc * 8, smem + 16384 + buf * 8192 + fl * 8);
        }
    };

    STAGE(0, 0);
    __syncthreads();
    int buf = 0;
    const int kbase = w * 32;   // this wave's kv slice within the 128-tile

    for (int t = 0; t < SS / 128; ++t) {
        if (t < SS / 128 - 1) STAGE(buf ^ 1, t + 1);
        const u16* ks = smem + buf * 8192;
        const u16* vs = smem + 16384 + buf * 8192;

        // K fragments for this wave's 32-kv slice (reused across 4 q-groups)
        bf16x8 kf[2][2];
#pragma unroll
        for (int kvg = 0; kvg < 2; ++kvg) {
            int row = kbase + kvg * 16 + l15;
            const u16* kr = ks + row * 64;
            kf[kvg][0] = *(const bf16x8*)&kr[((0 * 4 + hi) ^ (row & 7)) * 8];
            kf[kvg][1] = *(const bf16x8*)&kr[((1 * 4 + hi) ^ (row & 7)) * 8];
        }

        // QK^T: sc[qg][kvg][r], q = qg*16 + l15, kv(within slice) = kvg*16 + hi*4 + r
        f32x4 sc[4][2];
        __builtin_amdgcn_s_setprio(1);
#pragma unroll
        for (int qg = 0; qg < 4; ++qg)
#pragma unroll
            for (int kvg = 0; kvg < 2; ++kvg) {
                f32x4 a = f32x4{0.f, 0.f, 0.f, 0.f};
                a = mfma16(kf[kvg][0], bq[qg][0], a);
                a = mfma16(kf[kvg][1], bq[qg][1], a);
                sc[qg][kvg] = a;
            }
        __builtin_amdgcn_s_setprio(0);

        // P = 2^(sc - mrun), packed straight into PV A-frags (pure in-lane)
        bf16x8 pa[4];
#pragma unroll
        for (int qg = 0; qg < 4; ++qg) {
            bf16x8 v;
#pragma unroll
            for (int r = 0; r < 4; ++r) {
                v[r]     = (__bf16)exp2_fast(sc[qg][0][r] - mrun);
                v[4 + r] = (__bf16)exp2_fast(sc[qg][1][r] - mrun);
            }
            pa[qg] = v;
        }

        // V fragments for this wave's slice (chunks w*4..w*4+3), reused across q-groups
        bf16x8 bv[4];
#pragma unroll
        for (int di = 0; di < 4; ++di) {
            int d = di * 16 + l15;
            bv[di] = *(const bf16x8*)&vs[d * 128 + (((w * 4 + hi) ^ (d & 7)) * 8)];
        }

        // PV + row-sum on the MFMA pipe
        __builtin_amdgcn_s_setprio(1);
#pragma unroll
        for (int qg = 0; qg < 4; ++qg) {
            sacc[qg] = mfma16(pa[qg], ONES, sacc[qg]);
#pragma unroll
            for (int di = 0; di < 4; ++di)
                oacc[qg][di] = mfma16(pa[qg], bv[di], oacc[qg][di]);
        }
        __builtin_amdgcn_s_setprio(0);

        // deferred overflow guard (never triggers for this data; exact linear rescale)
        float mx = sacc[0][0];
#pragma unroll
        for (int qg = 0; qg < 4; ++qg)
#pragma unroll
            for (int r = 0; r < 4; ++r) mx = fmaxf(mx, sacc[qg][r]);
        if (__any(mx > 1.0e30f)) {
            const float dn = 5.421010862427522e-20f;   // 2^-64
            mrun += 64.f;
#pragma unroll
            for (int qg = 0; qg < 4; ++qg) {
#pragma unroll
                for (int r = 0; r < 4; ++r) sacc[qg][r] *= dn;
#pragma unroll
                for (int di = 0; di < 4; ++di)
#pragma unroll
                    for (int r = 0; r < 4; ++r) oacc[qg][di][r] *= dn;
            }
        }

        __syncthreads();
        buf ^= 1;
    }

    // ---- cross-wave reduction: O = sum_w oacc_w * 2^(mrun_w - mmax), same for l ----
    float* P4   = (float*)smem;            // [4][64][65]
    float* sred = P4 + 4 * 64 * 65;        // [4][64]
    float* smr  = sred + 4 * 64;           // [4]
#pragma unroll
    for (int qg = 0; qg < 4; ++qg) {
        int q = qg * 16 + hi * 4;
#pragma unroll
        for (int di = 0; di < 4; ++di)
#pragma unroll
            for (int r = 0; r < 4; ++r)
                P4[(size_t)(w * 64 + q + r) * 65 + di * 16 + l15] = oacc[qg][di][r];
        if (l15 == 0) {
#pragma unroll
            for (int r = 0; r < 4; ++r) sred[w * 64 + q + r] = sacc[qg][r];
        }
    }
    if (lane == 0) smr[w] = mrun;
    __syncthreads();

    float mmax = fmaxf(fmaxf(smr[0], smr[1]), fmaxf(smr[2], smr[3]));
    float wsc[4];
#pragma unroll
    for (int sw = 0; sw < 4; ++sw) wsc[sw] = exp2_fast(smr[sw] - mmax);

    // wave w finalizes q-rows [w*16, w*16+16)
    float rs[4];
#pragma unroll
    for (int r = 0; r < 4; ++r) {
        int q = w * 16 + hi * 4 + r;
        float s = 0.f;
#pragma unroll
        for (int sw = 0; sw < 4; ++sw) s += sred[sw * 64 + q] * wsc[sw];
        rs[r] = 1.f / s;
    }
#pragma unroll
    for (int di = 0; di < 4; ++di) {
        int col = h * 64 + di * 16 + l15;
#pragma unroll
        for (int r = 0; r < 4; ++r) {
            int q = w * 16 + hi * 4 + r;
            float o = 0.f;
#pragma unroll
            for (int sw = 0; sw < 4; ++sw)
                o += P4[(size_t)(sw * 64 + q) * 65 + di * 16 + l15] * wsc[sw];
            cat[(size_t)(qt * 64 + q) * EE + col] = f2bf(o * rs[r]);
        }
    }
}

// ---------------- fused (4 bf16 partials + bias + bf16 residual) + layernorm ----------------
// res == hb is safe: each thread reads its own columns before writing them.
template<bool FINAL>
__launch_bounds__(256)
__global__ void add_ln4(const u16* __restrict__ o, const float* __restrict__ ob,
                        const u16* __restrict__ res,
                        const float* __restrict__ g, const float* __restrict__ b,
                        float* __restrict__ fout, u16* __restrict__ hb) {
    const int row = blockIdx.x, tid = threadIdx.x;
    const int w = tid >> 6, lane = tid & 63;
    float x0, x1, x2, x3;
    {
        ushort4 r4 = ((const ushort4*)(res + (size_t)row * EE))[tid];
        float4 ob4 = ((const float4*)ob)[tid];
        x0 = bf2f(r4.x) + ob4.x; x1 = bf2f(r4.y) + ob4.y;
        x2 = bf2f(r4.z) + ob4.z; x3 = bf2f(r4.w) + ob4.w;
    }
#pragma unroll
    for (int z = 0; z < 4; ++z) {
        ushort4 a4 = ((const ushort4*)(o + (size_t)z * SS * EE + (size_t)row * EE))[tid];
        x0 += bf2f(a4.x); x1 += bf2f(a4.y); x2 += bf2f(a4.z); x3 += bf2f(a4.w);
    }
    float s = x0 + x1 + x2 + x3;
    float q = x0 * x0 + x1 * x1 + x2 * x2 + x3 * x3;
#pragma unroll
    for (int off = 1; off < 64; off <<= 1) { s += __shfl_xor(s, off); q += __shfl_xor(q, off); }
    __shared__ float red[8];
    if (lane == 0) { red[w] = s; red[4 + w] = q; }
    __syncthreads();
    s = red[0] + red[1] + red[2] + red[3];
    q = red[4] + red[5] + red[6] + red[7];
    const float mu = s * (1.f / EE);
    const float var = q * (1.f / EE) - mu * mu;
    const float rstd = rsqrtf(var + 1e-5f);
    const int c0 = tid * 4;
    float y0 = (x0 - mu) * rstd * g[c0 + 0] + b[c0 + 0];
    float y1 = (x1 - mu) * rstd * g[c0 + 1] + b[c0 + 1];
    float y2 = (x2 - mu) * rstd * g[c0 + 2] + b[c0 + 2];
    float y3 = (x3 - mu) * rstd * g[c0 + 3] + b[c0 + 3];
    if (FINAL) ((float4*)(fout + (size_t)row * EE))[tid] = make_float4(y0, y1, y2, y3);
    store_bf4(hb + (size_t)row * EE + c0, y0, y1, y2, y3);
}

// ---------------- launch ----------------
extern "C" void kernel_launch(void* const* d_in, const int* in_sizes, int n_in,
                              void* d_out, int out_size, void* d_ws, size_t ws_size,
                              hipStream_t stream) {
    const float* x    = (const float*)d_in[0];
    const float* Wk   = (const float*)d_in[1];
    const float* Wq   = (const float*)d_in[2];
    const float* Wv   = (const float*)d_in[3];
    const float* hWk  = (const float*)d_in[4];
    const float* hbk  = (const float*)d_in[5];
    const float* hWq  = (const float*)d_in[6];
    const float* hbq  = (const float*)d_in[7];
    const float* hWv  = (const float*)d_in[8];
    const float* hbv  = (const float*)d_in[9];
    const float* Wo   = (const float*)d_in[10];
    const float* bo   = (const float*)d_in[11];
    const float* ln1g = (const float*)d_in[12];
    const float* ln1b = (const float*)d_in[13];
    const float* W1   = (const float*)d_in[14];
    const float* b1   = (const float*)d_in[15];
    const float* W2   = (const float*)d_in[16];
    const float* b2   = (const float*)d_in[17];
    const float* ln2g = (const float*)d_in[18];
    const float* ln2b = (const float*)d_in[19];

    char* ws = (char*)d_ws;
    u16*   WF   = (u16*)(ws + OFF_WF);
    u16*   HWT  = (u16*)(ws + OFF_HWT);
    u16*   WSHT = (u16*)(ws + OFF_WSHT);
    float* HB   = (float*)(ws + OFF_HB);
    u16*   WOT  = (u16*)(ws + OFF_WOT);
    u16*   W1T  = (u16*)(ws + OFF_W1T);
    u16*   W2T  = (u16*)(ws + OFF_W2T);
    u16*   HBF  = (u16*)(ws + OFF_HBF);
    u16*   QKVH = (u16*)(ws + OFF_QKVH);
    u16*   VT   = (u16*)(ws + OFF_VT);
    u16*   CAT  = (u16*)(ws + OFF_CAT);
    u16*   F1   = (u16*)(ws + OFF_F1);
    u16*   OFb  = (u16*)(ws + OFF_OF);

    // ---- prep (one-time) ----
    pos_add<<<SS, 256, 0, stream>>>(x, HBF);
    pack_bias<<<72, 256, 0, stream>>>(hbk, hbq, hbv, HB);
    hw_t3<<<dim3(1, 1, 288), 256, 0, stream>>>(hWk, hWq, hWv, HWT);
    wsh_t3<<<dim3(16, 1, 3), 256, 0, stream>>>(Wk, Wq, Wv, WSHT);
    // fused weights WF[t][l][hd][e], batched over t
    gemm_std<0, false, false, true><<<dim3(8, 48, 3), 256, 0, stream>>>(
        HWT, WSHT, nullptr, WF, 6144, 1024, 64, 64, 64,
        (long)96 * 4096, 65536, (long)6144 * 1024);
    // all-layer weight transposes
    transpose_cast64<<<dim3(16, 16, LL), 256, 0, stream>>>(Wo, WOT, EE, EE, (long)EE * EE, (long)EE * EE);
    transpose_cast64<<<dim3(64, 16, LL), 256, 0, stream>>>(W1, W1T, EE, FF, (long)EE * FF, (long)FF * EE);
    transpose_cast64<<<dim3(16, 64, LL), 256, 0, stream>>>(W2, W2T, FF, EE, (long)FF * EE, (long)EE * FF);

    for (int l = 0; l < LL; ++l) {
        // fused K/Q/V projections (Q pre-scaled to log2 domain; V transposed+permuted)
        gemm_qkv<<<dim3(24, 16, 1), 256, 0, stream>>>(HBF, WF, l, HB + (size_t)l * 3072, QKVH, VT);

        attn_fwd<<<512, 256, 0, stream>>>(QKVH, VT, CAT);

        // Wo projection, split-K=4 -> bf16 partials
        gemm_std<0, false, true, false><<<dim3(8, 16, 4), 256, 0, stream>>>(
            CAT, WOT + (size_t)l * EE * EE, nullptr, OFb, SS, EE, 256, 1024, 1024, 0, 0, 0);
        add_ln4<false><<<SS, 256, 0, stream>>>(OFb, bo + (size_t)l * EE, HBF,
                                               ln1g + (size_t)l * EE, ln1b + (size_t)l * EE,
                                               nullptr, HBF);

        // FFN
        gemm_std<1, true, false, false><<<dim3(32, 16, 1), 256, 0, stream>>>(
            HBF, W1T + (size_t)l * FF * EE, b1 + (size_t)l * FF, F1, SS, FF, 1024, 1024, 1024, 0, 0, 0);
        gemm_std<0, false, true, false><<<dim3(8, 16, 4), 256, 0, stream>>>(
            F1, W2T + (size_t)l * EE * FF, nullptr, OFb, SS, EE, 1024, 4096, 4096, 0, 0, 0);
        if (l == LL - 1)
            add_ln4<true><<<SS, 256, 0, stream>>>(OFb, b2 + (size_t)l * EE, HBF,
                                                  ln2g + (size_t)l * EE, ln2b + (size_t)l * EE,
                                                  (float*)d_out, HBF);
        else
            add_ln4<false><<<SS, 256, 0, stream>>>(OFb, b2 + (size_t)l * EE, HBF,
                                                   ln2g + (size_t)l * EE, ln2b + (size_t)l * EE,
                                                   nullptr, HBF);
    }
}

// Round 2
// 917.338 us; speedup vs baseline: 1.0256x; 1.0146x over previous
//
#include <hip/hip_runtime.h>
#include <stdint.h>

typedef unsigned short u16;
typedef unsigned int   u32;

constexpr int SS = 2048, EE = 1024, HH = 16, DD = 64, LL = 6, FF = 4096;

typedef __bf16 bf16x8 __attribute__((ext_vector_type(8)));
typedef float  f32x4  __attribute__((ext_vector_type(4)));

#define DEV __device__ __forceinline__
#define AS1 __attribute__((address_space(1)))
#define AS3 __attribute__((address_space(3)))

DEV u16 f2bf(float f) {
    u32 u = __builtin_bit_cast(u32, f);
    u += 0x7FFFu + ((u >> 16) & 1u);
    return (u16)(u >> 16);
}

DEV float bf2f(u16 v) { return __builtin_bit_cast(float, (u32)v << 16); }

DEV void store_bf4(u16* p, float a, float b, float c, float d) {
    u32 lo = (u32)f2bf(a) | ((u32)f2bf(b) << 16);
    u32 hi = (u32)f2bf(c) | ((u32)f2bf(d) << 16);
    *(uint2*)p = make_uint2(lo, hi);
}

DEV void gload16(const void* g, void* l) {
    __builtin_amdgcn_global_load_lds((const AS1 void*)g, (AS3 void*)l, 16, 0, 0);
}

DEV f32x4 mfma16(bf16x8 a, bf16x8 b, f32x4 c) {
    return __builtin_amdgcn_mfma_f32_16x16x32_bf16(a, b, c, 0, 0, 0);
}

// single-instruction 2^x (VOP1 v_exp_f32)
DEV float exp2_fast(float x) {
    float r;
    asm("v_exp_f32 %0, %1" : "=v"(r) : "v"(x));
    return r;
}

// kv-permutation: actual kv -> PV-consumption slot (bit-6 transparent)
DEV int kvperm(int c) {
    return (c & 32) | ((c & 12) << 1) | ((c & 16) >> 2) | (c & 3);
}

// XCD-chunked bijective swizzle over nwg blocks (nwg % 8 == 0)
DEV int xcd_swz(int flat, int nwg) {
    int chunk = nwg >> 3;
    return (flat & 7) * chunk + (flat >> 3);
}

// ---------------- workspace layout (bytes) ----------------
constexpr size_t ALGN(size_t x) { return (x + 255) & ~(size_t)255; }
constexpr size_t OFF_WSHB = 0;                                            // [3][64][1024] bf16 (shared W, cast)
constexpr size_t OFF_HVB  = ALGN(OFF_WSHB + (size_t)3*64*1024*2);         // [96][64][64] bf16 (hWv cast)
constexpr size_t OFF_KQV3 = ALGN(OFF_HVB  + (size_t)96*4096*2);           // [3][2048][64] bf16 (K',Q',V')
constexpr size_t OFF_WVOT = ALGN(OFF_KQV3 + (size_t)3*SS*64*2);           // [L][E][E] bf16 (hWv@Wo)^T-ish
constexpr size_t OFF_BO2  = ALGN(OFF_WVOT + (size_t)LL*EE*EE*2);          // [L][E] f32 (bv@Wo + bo)
constexpr size_t OFF_HWT  = ALGN(OFF_BO2  + (size_t)LL*EE*4);             // [3][96][64][64] bf16
constexpr size_t OFF_HB   = ALGN(OFF_HWT  + (size_t)3*96*4096*2);         // [L][3][H][64] f32
constexpr size_t OFF_WOT  = ALGN(OFF_HB   + (size_t)LL*3*HH*64*4);        // [L][E][E] bf16 (Wo^T)
constexpr size_t OFF_W1T  = ALGN(OFF_WOT  + (size_t)LL*EE*EE*2);          // [L][FF][E] bf16
constexpr size_t OFF_W2T  = ALGN(OFF_W1T  + (size_t)LL*FF*EE*2);          // [L][E][FF] bf16
constexpr size_t OFF_HBF  = ALGN(OFF_W2T  + (size_t)LL*EE*FF*2);          // h bf16 [S][E] (residual chain)
// transient union: [QKVH 2*16*S*64 | VT 64*S | CAT S*E] bf16 ; F1 [S][FF] bf16 aliases whole region
constexpr size_t OFF_QKVH = ALGN(OFF_HBF  + (size_t)SS*EE*2);
constexpr size_t OFF_VT   = OFF_QKVH + (size_t)2*HH*SS*64*2;
constexpr size_t OFF_CAT  = OFF_VT   + (size_t)64*SS*2;
constexpr size_t OFF_F1   = OFF_QKVH;                                     // alias
constexpr size_t OFF_OF   = ALGN(OFF_F1  + (size_t)SS*FF*2);              // [4][S][E] bf16 partials

// ---------------- prep kernels ----------------
__global__ void pos_add(const float* __restrict__ x, u16* __restrict__ hb) {
    const int row = blockIdx.x, tid = threadIdx.x;
    float4 x4 = ((const float4*)(x + (size_t)row * EE))[tid];
    float v[4] = {x4.x, x4.y, x4.z, x4.w};
    float y[4];
#pragma unroll
    for (int j = 0; j < 4; ++j) {
        int e = tid * 4 + j;
        float ang = (float)row * expf((float)e * (-9.210340371976184f / 1024.f));
        float pe = ((row & 1) == 0) ? sinf(ang) : cosf(ang);
        y[j] = v[j] + pe;
    }
    store_bf4(hb + (size_t)row * EE + tid * 4, y[0], y[1], y[2], y[3]);
}

__global__ void pack_bias(const float* __restrict__ bk, const float* __restrict__ bq,
                          const float* __restrict__ bv, float* __restrict__ dst) {
    int i = blockIdx.x * 256 + threadIdx.x;      // [l][t][h][64]
    if (i >= LL * 3 * HH * 64) return;
    int d = i & 63;
    int hh = (i >> 6) & 15;
    int lt = i >> 10;
    int t = lt % 3, l = lt / 3;
    const float* s = (t == 0) ? bk : (t == 1) ? bq : bv;
    dst[i] = s[((size_t)l * HH + hh) * 64 + d];
}

// 64x64 tile transpose-cast body (src f32 [R][C] -> dst bf16 [C][R])
DEV void tile_t64(const float* src, u16* dst, int R, int C, int c0, int r0,
                  float (*t)[65], int tid) {
    const int lr = tid >> 4, lc4 = (tid & 15) * 4;
#pragma unroll
    for (int i = 0; i < 4; ++i) {
        int r = i * 16 + lr;
        float4 v = *(const float4*)(src + (size_t)(r0 + r) * C + c0 + lc4);
        t[r][lc4] = v.x; t[r][lc4 + 1] = v.y; t[r][lc4 + 2] = v.z; t[r][lc4 + 3] = v.w;
    }
    __syncthreads();
    const int cr = tid >> 3, rr8 = (tid & 7) * 8;
#pragma unroll
    for (int i = 0; i < 2; ++i) {
        int cc = i * 32 + cr;
        u16 tmp[8];
#pragma unroll
        for (int j = 0; j < 8; ++j) tmp[j] = f2bf(t[rr8 + j][cc]);
        *(uint4*)(dst + (size_t)(c0 + cc) * R + r0 + rr8) = *(uint4*)tmp;
    }
}

// f32 [b][R][C] -> bf16 [b][C][R], 64x64 tiles
__global__ void transpose_cast64(const float* __restrict__ src, u16* __restrict__ dst,
                                 int R, int C, long sSrc, long sDst) {
    __shared__ float t[64][65];
    const int b = blockIdx.z;
    tile_t64(src + (size_t)b * sSrc, dst + (size_t)b * sDst, R, C,
             blockIdx.x * 64, blockIdx.y * 64, t, threadIdx.x);
}

// merged per-head weight transpose: z in [0,192), t=z/96, head-idx=z%96 (k,q only)
__global__ void hw_t3(const float* __restrict__ s0, const float* __restrict__ s1,
                      const float* __restrict__ s2, u16* __restrict__ dst) {
    __shared__ float t[64][65];
    const int z = blockIdx.z;
    const float* src = (z < 96 ? s0 : z < 192 ? s1 : s2) + (size_t)(z % 96) * 4096;
    tile_t64(src, dst + (size_t)z * 4096, 64, 64, 0, 0, t, threadIdx.x);
}

// cast-only: shared weights [64][1024] f32 -> bf16 (no transpose; B operand is [N][K])
__global__ void wsh_cast(const float* __restrict__ s0, const float* __restrict__ s1,
                         const float* __restrict__ s2, u16* __restrict__ dst) {
    const int z = blockIdx.z, row = blockIdx.x, tid = threadIdx.x;
    const float* s = (z == 0 ? s0 : z == 1 ? s1 : s2) + (size_t)row * 1024 + tid * 4;
    float4 v = *(const float4*)s;
    store_bf4(dst + ((size_t)z * 64 + row) * 1024 + tid * 4, v.x, v.y, v.z, v.w);
}

// cast-only: hWv [L*H][64][64] f32 -> bf16
__global__ void hv_cast(const float* __restrict__ src, u16* __restrict__ dst) {
    size_t i = ((size_t)blockIdx.x * 256 + threadIdx.x) * 4;
    float4 v = *(const float4*)(src + i);
    store_bf4(dst + i, v.x, v.y, v.z, v.w);
}

// BO2[l][e] = bo[l][e] + sum_j hbv_cat[l][j] * Wo[l][j][e]   (exact: softmax rows sum to 1)
__global__ void bo_fold(const float* __restrict__ bo, const float* __restrict__ hbv,
                        const float* __restrict__ Wo, float* __restrict__ BO2) {
    const int l = blockIdx.z, e = blockIdx.x * 256 + threadIdx.x;
    float acc = bo[(size_t)l * EE + e];
    const float* w = Wo + (size_t)l * EE * EE + e;
    const float* bv = hbv + (size_t)l * EE;
    for (int j = 0; j < EE; ++j) acc += bv[j] * w[(size_t)j * EE];
    BO2[(size_t)l * EE + e] = acc;
}

// ---------------- TN GEMM, double-buffered, XCD-swizzled ----------------
// out is always bf16. SPLITK: out offset z*M*N (K split by grid.z).
// BATCH: z indexes independent problems with strides zsA/zsB/zsC.
// BIASMODE: 0 none, 1 per-col
template<int BIASMODE, bool RELU, bool SPLITK, bool BATCH>
__launch_bounds__(256)
__global__ void gemm_std(const u16* __restrict__ A, const u16* __restrict__ B,
                         const float* __restrict__ bias, u16* __restrict__ Cb,
                         int M, int N, int K, int lda, int ldb,
                         long zsA, long zsB, long zsC) {
    __shared__ u16 As[2][128 * 64];
    __shared__ u16 Bs[2][128 * 64];
    const int gx = gridDim.x;
    const int swz = xcd_swz(blockIdx.y * gx + blockIdx.x, gx * gridDim.y);
    const int bn = swz % gx, bm = swz / gx, z = blockIdx.z;
    const int tid = threadIdx.x, w = tid >> 6;
    const int lane = tid & 63, l15 = lane & 15, hi = lane >> 4;
    const int wm = w >> 1, wn = w & 1;
    const u16* Ab = A + (size_t)bm * 128 * lda + (SPLITK ? (size_t)z * K : 0) + (BATCH ? (size_t)z * zsA : 0);
    const u16* Bb = B + (size_t)bn * 128 * ldb + (SPLITK ? (size_t)z * K : 0) + (BATCH ? (size_t)z * zsB : 0);
    const size_t coff = SPLITK ? (size_t)z * M * N : (BATCH ? (size_t)z * zsC : 0);
    const int tr = tid >> 3, tp = tid & 7;

    f32x4 acc[4][4];
#pragma unroll
    for (int i = 0; i < 4; ++i)
#pragma unroll
        for (int j = 0; j < 4; ++j) acc[i][j] = f32x4{0.f, 0.f, 0.f, 0.f};

    auto STAGE = [&](int b, int kt) {
        const u16* Abk = Ab + kt + (size_t)tr * lda + tp * 8;
        const u16* Bbk = Bb + kt + (size_t)tr * ldb + tp * 8;
#pragma unroll
        for (int i = 0; i < 4; ++i) {
            gload16(Abk + (size_t)i * 32 * lda, &As[b][(i * 256 + w * 64) * 8]);
            gload16(Bbk + (size_t)i * 32 * ldb, &Bs[b][(i * 256 + w * 64) * 8]);
        }
    };

    STAGE(0, 0);
    __syncthreads();
    int buf = 0;

    for (int kt = 0; kt < K; kt += 64) {
        if (kt + 64 < K) STAGE(buf ^ 1, kt + 64);
#pragma unroll
        for (int kk = 0; kk < 2; ++kk) {
            bf16x8 af[4], bf[4];
#pragma unroll
            for (int mi = 0; mi < 4; ++mi)
                af[mi] = *(const bf16x8*)&As[buf][(wm * 64 + mi * 16 + l15) * 64 + kk * 32 + hi * 8];
#pragma unroll
            for (int ni = 0; ni < 4; ++ni)
                bf[ni] = *(const bf16x8*)&Bs[buf][(wn * 64 + ni * 16 + l15) * 64 + kk * 32 + hi * 8];
#pragma unroll
            for (int mi = 0; mi < 4; ++mi)
#pragma unroll
                for (int ni = 0; ni < 4; ++ni)
                    acc[mi][ni] = mfma16(af[mi], bf[ni], acc[mi][ni]);
        }
        __syncthreads();
        buf ^= 1;
    }

#pragma unroll
    for (int mi = 0; mi < 4; ++mi) {
        int rg = bm * 128 + wm * 64 + mi * 16 + hi * 4;
#pragma unroll
        for (int ni = 0; ni < 4; ++ni) {
            int cg = bn * 128 + wn * 64 + ni * 16 + l15;
            float bc = (BIASMODE == 1) ? bias[cg] : 0.f;
#pragma unroll
            for (int r = 0; r < 4; ++r) {
                float v = acc[mi][ni][r] + bc;
                if (RELU) v = fmaxf(v, 0.f);
                Cb[coff + (size_t)(rg + r) * N + cg] = f2bf(v);
            }
        }
    }
}

// ---------------- small TN GEMM: 64x64 tile, BK=64, 4 waves (2x2), 32KB LDS ----------------
// EPI 0: plain bf16 C at zq*cL + zr*cS + rg*ldc + cn
// EPI 1: stage-2 per-head K/Q -> QKVH[z][s][d], bias[z*64+d], Q (z>=16) pre-scaled to log2 dom
// EPI 3: stage-1 shared proj: z<2 -> C0 (KQV3) + z*SS*64 (ldc 64); z==2 -> VT[d][psi(s)] (C1)
template<int EPI>
__launch_bounds__(256)
__global__ void gemm_small(const u16* __restrict__ A, const u16* __restrict__ B,
                           const float* __restrict__ bias, u16* __restrict__ C0,
                           u16* __restrict__ C1,
                           int K, int lda, int ldb, int ldc, int zdiv,
                           long aL, long aS, long bL, long bS, long cL, long cS) {
    __shared__ u16 As[2][64 * 64];
    __shared__ u16 Bs[2][64 * 64];
    const int bm = blockIdx.x, z = blockIdx.z;
    const int zq = z / zdiv, zr = z % zdiv;
    const int tid = threadIdx.x, w = tid >> 6;
    const int lane = tid & 63, l15 = lane & 15, hi = lane >> 4;
    const int wm = w >> 1, wn = w & 1;
    const u16* Ab = A + (size_t)bm * 64 * lda + (size_t)zq * aL + (size_t)zr * aS;
    const u16* Bb = B + (size_t)zq * bL + (size_t)zr * bS;
    const int tr = tid >> 3, tp = tid & 7;

    f32x4 acc[2][2];
#pragma unroll
    for (int i = 0; i < 2; ++i)
#pragma unroll
        for (int j = 0; j < 2; ++j) acc[i][j] = f32x4{0.f, 0.f, 0.f, 0.f};

    auto STAGE = [&](int b, int kt) {
        const u16* Abk = Ab + kt + (size_t)tr * lda + tp * 8;
        const u16* Bbk = Bb + kt + (size_t)tr * ldb + tp * 8;
#pragma unroll
        for (int i = 0; i < 2; ++i) {
            gload16(Abk + (size_t)i * 32 * lda, &As[b][(i * 256 + tid) * 8]);
            gload16(Bbk + (size_t)i * 32 * ldb, &Bs[b][(i * 256 + tid) * 8]);
        }
    };

    STAGE(0, 0);
    __syncthreads();
    int buf = 0;

    for (int kt = 0; kt < K; kt += 64) {
        if (kt + 64 < K) STAGE(buf ^ 1, kt + 64);
#pragma unroll
        for (int kk = 0; kk < 2; ++kk) {
            bf16x8 af[2], bf[2];
#pragma unroll
            for (int mi = 0; mi < 2; ++mi)
                af[mi] = *(const bf16x8*)&As[buf][(wm * 32 + mi * 16 + l15) * 64 + kk * 32 + hi * 8];
#pragma unroll
            for (int ni = 0; ni < 2; ++ni)
                bf[ni] = *(const bf16x8*)&Bs[buf][(wn * 32 + ni * 16 + l15) * 64 + kk * 32 + hi * 8];
#pragma unroll
            for (int mi = 0; mi < 2; ++mi)
#pragma unroll
                for (int ni = 0; ni < 2; ++ni)
                    acc[mi][ni] = mfma16(af[mi], bf[ni], acc[mi][ni]);
        }
        __syncthreads();
        buf ^= 1;
    }

#pragma unroll
    for (int mi = 0; mi < 2; ++mi) {
        const int rg = bm * 64 + wm * 32 + mi * 16 + hi * 4;
#pragma unroll
        for (int ni = 0; ni < 2; ++ni) {
            const int cn = wn * 32 + ni * 16 + l15;
            if (EPI == 0) {
#pragma unroll
                for (int r = 0; r < 4; ++r)
                    C0[(size_t)zq * cL + (size_t)zr * cS + (size_t)(rg + r) * ldc + cn] =
                        f2bf(acc[mi][ni][r]);
            } else if (EPI == 1) {
                const float sc = (z >= 16) ? 0.18033688011112042f : 1.f;  // Q: 0.125*log2(e)
                const float bv = bias[z * 64 + cn];
                u16* dst = C0 + ((size_t)z * SS + rg) * 64 + cn;
#pragma unroll
                for (int r = 0; r < 4; ++r)
                    dst[(size_t)r * 64] = f2bf((acc[mi][ni][r] + bv) * sc);
            } else {  // EPI == 3
                if (z < 2) {
#pragma unroll
                    for (int r = 0; r < 4; ++r)
                        C0[(size_t)z * SS * 64 + (size_t)(rg + r) * 64 + cn] = f2bf(acc[mi][ni][r]);
                } else {
                    const int ps = (rg & ~63) | kvperm(rg & 63);   // r 0..3 stays contiguous
                    u16 tmp[4];
#pragma unroll
                    for (int r = 0; r < 4; ++r) tmp[r] = f2bf(acc[mi][ni][r]);
                    *(uint2*)(C1 + (size_t)cn * SS + ps) = *(uint2*)tmp;
                }
            }
        }
    }
}

// ---------------- flash attention (swapped QK^T, exp2 softmax, KVBLK=128) ----------------
// kv-slice-per-wave; V is the SHARED V' (64 x S, ~256KB, L2-hot); per-head output is
// attn_h @ V' (the hWv/Wo projections are folded into the Wo GEMM via WVOT).
__launch_bounds__(256)
__global__ void attn_fwd(const u16* __restrict__ QKVH, const u16* __restrict__ VT,
                         u16* __restrict__ cat) {
    const int logical = (blockIdx.x & 7) * 64 + (blockIdx.x >> 3);  // bijective: 512 = 8 x 64
    const int h = logical >> 5, qt = logical & 31;
    const int tid = threadIdx.x, w = tid >> 6, lane = tid & 63;
    const int l15 = lane & 15, hi = lane >> 4;
    // main loop: [0,8192) Ks buf0 | [8192,16384) Ks buf1 | [16384,24576) Vs buf0 | ... (u16)
    // epilogue reuse: P4 f32[4][64][65] | sred f32[4][64] | smr f32[4]
    __shared__ __align__(16) u16 smem[33824];

    const u16* qb = QKVH + (((size_t)(16 + h) * SS) + qt * 64) * 64;
    const u16* kb = QKVH + ((size_t)h * SS) * 64;
    const u16* vb = VT;

    // all 64 q-rows of the block, register-resident per wave
    bf16x8 bq[4][2];
#pragma unroll
    for (int qg = 0; qg < 4; ++qg) {
        bq[qg][0] = *(const bf16x8*)(qb + (qg * 16 + l15) * 64 + hi * 8);
        bq[qg][1] = *(const bf16x8*)(qb + (qg * 16 + l15) * 64 + 32 + hi * 8);
    }
    bf16x8 ONES;
#pragma unroll
    for (int i = 0; i < 8; ++i) ONES[i] = (__bf16)1.0f;

    f32x4 oacc[4][4];   // [qg][di], q = qg*16 + hi*4 + r, d = di*16 + l15
#pragma unroll
    for (int i = 0; i < 4; ++i)
#pragma unroll
        for (int j = 0; j < 4; ++j) oacc[i][j] = f32x4{0.f, 0.f, 0.f, 0.f};
    f32x4 sacc[4];      // [qg] row sums, q = qg*16 + hi*4 + r
#pragma unroll
    for (int i = 0; i < 4; ++i) sacc[i] = f32x4{0.f, 0.f, 0.f, 0.f};
    float mrun = 0.f;

    auto STAGE = [&](int buf, int t) {
#pragma unroll
        for (int j = 0; j < 4; ++j) {
            int fl = j * 256 + tid;                     // 0..1023 chunk id
            int kr = fl >> 3, kc = (fl & 7) ^ (kr & 7); // K: 128 rows x 8 chunks
            gload16(kb + ((size_t)(t * 128 + kr)) * 64 + kc * 8, smem + buf * 8192 + fl * 8);
            int vr = fl >> 4, vc = (fl & 15) ^ (vr & 7); // V: 64 d-rows x 16 chunks
            gload16(vb + (size_t)vr * SS + t * 128 + vc * 8, smem + 16384 + buf * 8192 + fl * 8);
        }
    };

    STAGE(0, 0);
    __syncthreads();
    int buf = 0;
    const int kbase = w * 32;   // this wave's kv slice within the 128-tile

    for (int t = 0; t < SS / 128; ++t) {
        if (t < SS / 128 - 1) STAGE(buf ^ 1, t + 1);
        const u16* ks = smem + buf * 8192;
        const u16* vs = smem + 16384 + buf * 8192;

        // K fragments for this wave's 32-kv slice (reused across 4 q-groups)
        bf16x8 kf[2][2];
#pragma unroll
        for (int kvg = 0; kvg < 2; ++kvg) {
            int row = kbase + kvg * 16 + l15;
            const u16* kr = ks + row * 64;
            kf[kvg][0] = *(const bf16x8*)&kr[((0 * 4 + hi) ^ (row & 7)) * 8];
            kf[kvg][1] = *(const bf16x8*)&kr[((1 * 4 + hi) ^ (row & 7)) * 8];
        }

        // QK^T: sc[qg][kvg][r], q = qg*16 + l15, kv(within slice) = kvg*16 + hi*4 + r
        f32x4 sc[4][2];
        __builtin_amdgcn_s_setprio(1);
#pragma unroll
        for (int qg = 0; qg < 4; ++qg)
#pragma unroll
            for (int kvg = 0; kvg < 2; ++kvg) {
                f32x4 a = f32x4{0.f, 0.f, 0.f, 0.f};
                a = mfma16(kf[kvg][0], bq[qg][0], a);
                a = mfma16(kf[kvg][1], bq[qg][1], a);
                sc[qg][kvg] = a;
            }
        __builtin_amdgcn_s_setprio(0);

        // P = 2^(sc - mrun), packed straight into PV A-frags (pure in-lane)
        bf16x8 pa[4];
#pragma unroll
        for (int qg = 0; qg < 4; ++qg) {
            bf16x8 v;
#pragma unroll
            for (int r = 0; r < 4; ++r) {
                v[r]     = (__bf16)exp2_fast(sc[qg][0][r] - mrun);
                v[4 + r] = (__bf16)exp2_fast(sc[qg][1][r] - mrun);
            }
            pa[qg] = v;
        }

        // V fragments for this wave's slice (chunks w*4..w*4+3), reused across q-groups
        bf16x8 bv[4];
#pragma unroll
        for (int di = 0; di < 4; ++di) {
            int d = di * 16 + l15;
            bv[di] = *(const bf16x8*)&vs[d * 128 + (((w * 4 + hi) ^ (d & 7)) * 8)];
        }

        // PV + row-sum on the MFMA pipe
        __builtin_amdgcn_s_setprio(1);
#pragma unroll
        for (int qg = 0; qg < 4; ++qg) {
            sacc[qg] = mfma16(pa[qg], ONES, sacc[qg]);
#pragma unroll
            for (int di = 0; di < 4; ++di)
                oacc[qg][di] = mfma16(pa[qg], bv[di], oacc[qg][di]);
        }
        __builtin_amdgcn_s_setprio(0);

        // deferred overflow guard (never triggers for this data; exact linear rescale)
        float mx = sacc[0][0];
#pragma unroll
        for (int qg = 0; qg < 4; ++qg)
#pragma unroll
            for (int r = 0; r < 4; ++r) mx = fmaxf(mx, sacc[qg][r]);
        if (__any(mx > 1.0e30f)) {
            const float dn = 5.421010862427522e-20f;   // 2^-64
            mrun += 64.f;
#pragma unroll
            for (int qg = 0; qg < 4; ++qg) {
#pragma unroll
                for (int r = 0; r < 4; ++r) sacc[qg][r] *= dn;
#pragma unroll
                for (int di = 0; di < 4; ++di)
#pragma unroll
                    for (int r = 0; r < 4; ++r) oacc[qg][di][r] *= dn;
            }
        }

        __syncthreads();
        buf ^= 1;
    }

    // ---- cross-wave reduction: O = sum_w oacc_w * 2^(mrun_w - mmax), same for l ----
    float* P4   = (float*)smem;            // [4][64][65]
    float* sred = P4 + 4 * 64 * 65;        // [4][64]
    float* smr  = sred + 4 * 64;           // [4]
#pragma unroll
    for (int qg = 0; qg < 4; ++qg) {
        int q = qg * 16 + hi * 4;
#pragma unroll
        for (int di = 0; di < 4; ++di)
#pragma unroll
            for (int r = 0; r < 4; ++r)
                P4[(size_t)(w * 64 + q + r) * 65 + di * 16 + l15] = oacc[qg][di][r];
        if (l15 == 0) {
#pragma unroll
            for (int r = 0; r < 4; ++r) sred[w * 64 + q + r] = sacc[qg][r];
        }
    }
    if (lane == 0) smr[w] = mrun;
    __syncthreads();

    float mmax = fmaxf(fmaxf(smr[0], smr[1]), fmaxf(smr[2], smr[3]));
    float wsc[4];
#pragma unroll
    for (int sw = 0; sw < 4; ++sw) wsc[sw] = exp2_fast(smr[sw] - mmax);

    // wave w finalizes q-rows [w*16, w*16+16)
    float rs[4];
#pragma unroll
    for (int r = 0; r < 4; ++r) {
        int q = w * 16 + hi * 4 + r;
        float s = 0.f;
#pragma unroll
        for (int sw = 0; sw < 4; ++sw) s += sred[sw * 64 + q] * wsc[sw];
        rs[r] = 1.f / s;
    }
#pragma unroll
    for (int di = 0; di < 4; ++di) {
        int col = h * 64 + di * 16 + l15;
#pragma unroll
        for (int r = 0; r < 4; ++r) {
            int q = w * 16 + hi * 4 + r;
            float o = 0.f;
#pragma unroll
            for (int sw = 0; sw < 4; ++sw)
                o += P4[(size_t)(sw * 64 + q) * 65 + di * 16 + l15] * wsc[sw];
            cat[(size_t)(qt * 64 + q) * EE + col] = f2bf(o * rs[r]);
        }
    }
}

// ---------------- fused (4 bf16 partials + bias + bf16 residual) + layernorm ----------------
// res == hb is safe: each thread reads its own columns before writing them.
template<bool FINAL>
__launch_bounds__(256)
__global__ void add_ln4(const u16* __restrict__ o, const float* __restrict__ ob,
                        const u16* __restrict__ res,
                        const float* __restrict__ g, const float* __restrict__ b,
                        float* __restrict__ fout, u16* __restrict__ hb) {
    const int row = blockIdx.x, tid = threadIdx.x;
    const int w = tid >> 6, lane = tid & 63;
    float x0, x1, x2, x3;
    {
        ushort4 r4 = ((const ushort4*)(res + (size_t)row * EE))[tid];
        float4 ob4 = ((const float4*)ob)[tid];
        x0 = bf2f(r4.x) + ob4.x; x1 = bf2f(r4.y) + ob4.y;
        x2 = bf2f(r4.z) + ob4.z; x3 = bf2f(r4.w) + ob4.w;
    }
#pragma unroll
    for (int z = 0; z < 4; ++z) {
        ushort4 a4 = ((const ushort4*)(o + (size_t)z * SS * EE + (size_t)row * EE))[tid];
        x0 += bf2f(a4.x); x1 += bf2f(a4.y); x2 += bf2f(a4.z); x3 += bf2f(a4.w);
    }
    float s = x0 + x1 + x2 + x3;
    float q = x0 * x0 + x1 * x1 + x2 * x2 + x3 * x3;
#pragma unroll
    for (int off = 1; off < 64; off <<= 1) { s += __shfl_xor(s, off); q += __shfl_xor(q, off); }
    __shared__ float red[8];
    if (lane == 0) { red[w] = s; red[4 + w] = q; }
    __syncthreads();
    s = red[0] + red[1] + red[2] + red[3];
    q = red[4] + red[5] + red[6] + red[7];
    const float mu = s * (1.f / EE);
    const float var = q * (1.f / EE) - mu * mu;
    const float rstd = rsqrtf(var + 1e-5f);
    const int c0 = tid * 4;
    float y0 = (x0 - mu) * rstd * g[c0 + 0] + b[c0 + 0];
    float y1 = (x1 - mu) * rstd * g[c0 + 1] + b[c0 + 1];
    float y2 = (x2 - mu) * rstd * g[c0 + 2] + b[c0 + 2];
    float y3 = (x3 - mu) * rstd * g[c0 + 3] + b[c0 + 3];
    if (FINAL) ((float4*)(fout + (size_t)row * EE))[tid] = make_float4(y0, y1, y2, y3);
    store_bf4(hb + (size_t)row * EE + c0, y0, y1, y2, y3);
}

// ---------------- launch ----------------
extern "C" void kernel_launch(void* const* d_in, const int* in_sizes, int n_in,
                              void* d_out, int out_size, void* d_ws, size_t ws_size,
                              hipStream_t stream) {
    const float* x    = (const float*)d_in[0];
    const float* Wk   = (const float*)d_in[1];
    const float* Wq   = (const float*)d_in[2];
    const float* Wv   = (const float*)d_in[3];
    const float* hWk  = (const float*)d_in[4];
    const float* hbk  = (const float*)d_in[5];
    const float* hWq  = (const float*)d_in[6];
    const float* hbq  = (const float*)d_in[7];
    const float* hWv  = (const float*)d_in[8];
    const float* hbv  = (const float*)d_in[9];
    const float* Wo   = (const float*)d_in[10];
    const float* bo   = (const float*)d_in[11];
    const float* ln1g = (const float*)d_in[12];
    const float* ln1b = (const float*)d_in[13];
    const float* W1   = (const float*)d_in[14];
    const float* b1   = (const float*)d_in[15];
    const float* W2   = (const float*)d_in[16];
    const float* b2   = (const float*)d_in[17];
    const float* ln2g = (const float*)d_in[18];
    const float* ln2b = (const float*)d_in[19];

    char* ws = (char*)d_ws;
    u16*   WSHB = (u16*)(ws + OFF_WSHB);
    u16*   HVB  = (u16*)(ws + OFF_HVB);
    u16*   KQV3 = (u16*)(ws + OFF_KQV3);
    u16*   WVOT = (u16*)(ws + OFF_WVOT);
    float* BO2  = (float*)(ws + OFF_BO2);
    u16*   HWT  = (u16*)(ws + OFF_HWT);
    float* HB   = (float*)(ws + OFF_HB);
    u16*   WOT  = (u16*)(ws + OFF_WOT);
    u16*   W1T  = (u16*)(ws + OFF_W1T);
    u16*   W2T  = (u16*)(ws + OFF_W2T);
    u16*   HBF  = (u16*)(ws + OFF_HBF);
    u16*   QKVH = (u16*)(ws + OFF_QKVH);
    u16*   VT   = (u16*)(ws + OFF_VT);
    u16*   CAT  = (u16*)(ws + OFF_CAT);
    u16*   F1   = (u16*)(ws + OFF_F1);
    u16*   OFb  = (u16*)(ws + OFF_OF);

    // ---- prep (one-time) ----
    pos_add<<<SS, 256, 0, stream>>>(x, HBF);
    pack_bias<<<72, 256, 0, stream>>>(hbk, hbq, hbv, HB);
    hw_t3<<<dim3(1, 1, 192), 256, 0, stream>>>(hWk, hWq, hWv, HWT);
    wsh_cast<<<dim3(64, 1, 3), 256, 0, stream>>>(Wk, Wq, Wv, WSHB);
    hv_cast<<<384, 256, 0, stream>>>(hWv, HVB);
    bo_fold<<<dim3(4, 1, LL), 256, 0, stream>>>(bo, hbv, Wo, BO2);
    // all-layer weight transposes
    transpose_cast64<<<dim3(16, 16, LL), 256, 0, stream>>>(Wo, WOT, EE, EE, (long)EE * EE, (long)EE * EE);
    transpose_cast64<<<dim3(64, 16, LL), 256, 0, stream>>>(W1, W1T, EE, FF, (long)EE * FF, (long)FF * EE);
    transpose_cast64<<<dim3(16, 64, LL), 256, 0, stream>>>(W2, W2T, FF, EE, (long)FF * EE, (long)EE * FF);
    // WVOT[l][e][h*64+d] = sum_e' Wo[l][h*64+e', e] * hWv[l,h][d, e']   (batched 96x: M=1024,N=64,K=64)
    gemm_small<0><<<dim3(16, 1, 96), 256, 0, stream>>>(
        WOT, HVB, nullptr, WVOT, nullptr, 64, 1024, 64, 1024, 16,
        (long)EE * EE, 64, (long)16 * 4096, 4096, (long)EE * EE, 64);

    for (int l = 0; l < LL; ++l) {
        // stage-1: shared projections KQV' = h @ {Wk,Wq,Wv}^T  (z=t; V' -> VT permuted)
        gemm_small<3><<<dim3(32, 1, 3), 256, 0, stream>>>(
            HBF, WSHB, nullptr, KQV3, VT, 1024, 1024, 1024, 64, 64,
            0, 0, 0, (long)64 * 1024, 0, 0);
        // stage-2: per-head K/Q linears (z = t*16+h; Q pre-scaled), K=64
        gemm_small<1><<<dim3(32, 1, 32), 256, 0, stream>>>(
            KQV3, HWT + (size_t)l * 16 * 4096, HB + (size_t)l * 3072, QKVH, nullptr,
            64, 64, 64, 64, 16,
            (long)SS * 64, 0, (long)96 * 4096, 4096, 0, 0);

        attn_fwd<<<512, 256, 0, stream>>>(QKVH, VT, CAT);

        // Wo projection with folded hWv (WVOT), split-K=4 -> bf16 partials
        gemm_std<0, false, true, false><<<dim3(8, 16, 4), 256, 0, stream>>>(
            CAT, WVOT + (size_t)l * EE * EE, nullptr, OFb, SS, EE, 256, 1024, 1024, 0, 0, 0);
        add_ln4<false><<<SS, 256, 0, stream>>>(OFb, BO2 + (size_t)l * EE, HBF,
                                               ln1g + (size_t)l * EE, ln1b + (size_t)l * EE,
                                               nullptr, HBF);

        // FFN
        gemm_std<1, true, false, false><<<dim3(32, 16, 1), 256, 0, stream>>>(
            HBF, W1T + (size_t)l * FF * EE, b1 + (size_t)l * FF, F1, SS, FF, 1024, 1024, 1024, 0, 0, 0);
        gemm_std<0, false, true, false><<<dim3(8, 16, 4), 256, 0, stream>>>(
            F1, W2T + (size_t)l * EE * FF, nullptr, OFb, SS, EE, 1024, 4096, 4096, 0, 0, 0);
        if (l == LL - 1)
            add_ln4<true><<<SS, 256, 0, stream>>>(OFb, b2 + (size_t)l * EE, HBF,
                                                  ln2g + (size_t)l * EE, ln2b + (size_t)l * EE,
                                                  (float*)d_out, HBF);
        else
            add_ln4<false><<<SS, 256, 0, stream>>>(OFb, b2 + (size_t)l * EE, HBF,
                                                   ln2g + (size_t)l * EE, ln2b + (size_t)l * EE,
                                                   nullptr, HBF);
    }
}